// Round 3
// baseline (167.387 us; speedup 1.0000x reference)
//
#include <hip/hip_runtime.h>
#include <cstddef>
#include <cstdint>

#define BATCH 128
#define NF 7

typedef float v2f __attribute__((ext_vector_type(2)));

__device__ __forceinline__ v2f pk_fma(v2f a, v2f b, v2f c) {
    v2f d;
    asm("v_pk_fma_f32 %0, %1, %2, %3" : "=v"(d) : "v"(a), "v"(b), "v"(c));
    return d;
}

__device__ __forceinline__ v2f silu2(v2f a) {
    v2f t = a * -1.442695041f;
    v2f e;
    e.x = __builtin_amdgcn_exp2f(t.x);
    e.y = __builtin_amdgcn_exp2f(t.y);
    v2f d = e + 1.0f;
    v2f r;
    r.x = __builtin_amdgcn_rcpf(d.x);
    r.y = __builtin_amdgcn_rcpf(d.y);
    return a * r;
}

// feats layout: out[i][f][lane] as float2 {row b, row b+64}
__global__ void feats_kernel(const float* __restrict__ in, float* __restrict__ out,
                             int din, int do_elu) {
    int t = blockIdx.x * blockDim.x + threadIdx.x;
    if (t >= din * BATCH) return;
    int b = t & (BATCH - 1);
    int i = t >> 7;
    float v = in[b * din + i];
    if (do_elu) v = (v > 0.0f) ? v : (__builtin_amdgcn_exp2f(v * 1.442695041f) - 1.0f);
    float s1, c1, s2, c2, s4, c4;
    sincosf(v, &s1, &c1);
    sincosf(2.0f * v, &s2, &c2);
    sincosf(4.0f * v, &s4, &c4);
    float* o = out + (size_t)i * (NF * 128) + (b & 63) * 2 + (b >> 6);
    o[0 * 128] = v;
    o[1 * 128] = s1;
    o[2 * 128] = s2;
    o[3 * 128] = s4;
    o[4 * 128] = c1;
    o[5 * 128] = c2;
    o[6 * 128] = c4;
}

// Per-wave LDS region (576 floats): 32 rows x {w0,w0,...,w6,w6,b1,b1} (16 f) + 32 w2 pairs.
#define WREG 576
#define W2OFF 512

template <int DIN, int DOUT, int CHUNK>
__global__ __launch_bounds__(256, 8) void kan_kernel(
    const float* __restrict__ fx,   // [DIN][NF][64] of float2 pairs
    const float* __restrict__ W1,   // [DIN][DOUT][32][7]
    const float* __restrict__ W2,   // [DIN][DOUT][32]
    const float* __restrict__ B1,   // [DIN][DOUT][32]
    const float* __restrict__ B2,   // [DIN][DOUT]
    float* __restrict__ out)        // [BATCH][DOUT], pre-zeroed, atomic accum
{
    __shared__ float smem[4 * WREG];
    __shared__ float redbuf[4 * 128];
    const int j    = blockIdx.x;
    const int tid  = threadIdx.x;
    const int w    = tid >> 6;
    const int lane = tid & 63;
    const int wb   = w * WREG;
    const int i0   = blockIdx.y * CHUNK;

    v2f tot = (v2f)(0.0f);

    for (int t = 0; t < CHUNK / 4; ++t) {
        const int i = i0 + t * 4 + w;
        // ---- stage duplicated weight pairs into this wave's private LDS region ----
        const float* w1p = W1 + ((size_t)i * DOUT + j) * 224;
        if (lane < 56) {
            const float4 v = *(const float4*)(w1p + lane * 4);
            const float* vp = (const float*)&v;
            #pragma unroll
            for (int q = 0; q < 4; ++q) {
                int e = lane * 4 + q;
                int h = e / 7;
                int f = e - h * 7;
                v2f pp = {vp[q], vp[q]};
                *(v2f*)&smem[wb + h * 16 + f * 2] = pp;
            }
        }
        const float* b1p = B1 + ((size_t)i * DOUT + j) * 32;
        const float* w2p = W2 + ((size_t)i * DOUT + j) * 32;
        if (lane < 32) {
            float bv = b1p[lane];
            *(v2f*)&smem[wb + lane * 16 + 14] = (v2f){bv, bv};
        } else {
            float wv = w2p[lane - 32];
            *(v2f*)&smem[wb + W2OFF + (lane - 32) * 2] = (v2f){wv, wv};
        }

        // ---- per-lane feats: 2 batch rows packed as float2 ----
        const float* fp = fx + (size_t)i * (NF * 128) + lane * 2;
        v2f f[NF];
        #pragma unroll
        for (int ff = 0; ff < NF; ++ff) f[ff] = *(const v2f*)(fp + ff * 128);

        v2f o = (v2f)(0.0f);
        #pragma unroll
        for (int h4 = 0; h4 < 8; ++h4) {
            // w2 pairs for these 4 h's
            const float4 wq0 = *(const float4*)&smem[wb + W2OFF + h4 * 8];
            const float4 wq1 = *(const float4*)&smem[wb + W2OFF + h4 * 8 + 4];
            v2f w2p0 = {wq0.x, wq0.y}, w2p1 = {wq0.z, wq0.w};
            v2f w2p2 = {wq1.x, wq1.y}, w2p3 = {wq1.z, wq1.w};
            #pragma unroll
            for (int hh = 0; hh < 4; ++hh) {
                const int h = h4 * 4 + hh;
                const float4 q0 = *(const float4*)&smem[wb + h * 16];
                const float4 q1 = *(const float4*)&smem[wb + h * 16 + 4];
                const float4 q2 = *(const float4*)&smem[wb + h * 16 + 8];
                const float4 q3 = *(const float4*)&smem[wb + h * 16 + 12];
                v2f a = {q3.z, q3.w};                    // b1 pair
                a = pk_fma(f[0], (v2f){q0.x, q0.y}, a);
                a = pk_fma(f[1], (v2f){q0.z, q0.w}, a);
                a = pk_fma(f[2], (v2f){q1.x, q1.y}, a);
                a = pk_fma(f[3], (v2f){q1.z, q1.w}, a);
                a = pk_fma(f[4], (v2f){q2.x, q2.y}, a);
                a = pk_fma(f[5], (v2f){q2.z, q2.w}, a);
                a = pk_fma(f[6], (v2f){q3.x, q3.y}, a);
                v2f s = silu2(a);
                v2f wp = (hh == 0) ? w2p0 : (hh == 1) ? w2p1 : (hh == 2) ? w2p2 : w2p3;
                o = pk_fma(s, wp, o);
            }
        }
        float b2v = B2[(size_t)i * DOUT + j];
        tot += o + b2v;
    }

    // ---- block-level reduce over the 4 waves, then one atomic per (b, j) ----
    redbuf[w * 128 + lane]      = tot.x;
    redbuf[w * 128 + 64 + lane] = tot.y;
    __syncthreads();
    if (tid < 128) {
        float s = redbuf[tid] + redbuf[128 + tid] + redbuf[256 + tid] + redbuf[384 + tid];
        atomicAdd(&out[(size_t)tid * DOUT + j], s);
    }
}

// GLU gate + residual + BatchNorm(batch axis), one block per output column j.
__device__ __forceinline__ int shidx(int k, int b) { return (k << 7) + ((b + k) & 127); }

__global__ __launch_bounds__(128) void glu_bn_kernel(
    const float* __restrict__ h2,     // [BATCH][128]
    const float* __restrict__ resid,  // [BATCH][128]
    const float* __restrict__ g1w, const float* __restrict__ g1b,
    const float* __restrict__ g2w, const float* __restrict__ g2b,
    const float* __restrict__ bnw, const float* __restrict__ bnb,
    float* __restrict__ out)          // [BATCH][128]
{
    __shared__ float sh[128 * 128];
    const int j   = blockIdx.x;
    const int tid = threadIdx.x;

    for (int b2 = 0; b2 < 128; ++b2)
        sh[shidx(tid, b2)] = h2[(size_t)b2 * 128 + tid];
    __syncthreads();

    const float* g1r = g1w + (size_t)j * 128;
    const float* g2r = g2w + (size_t)j * 128;
    float d1 = g1b[j], d2 = g2b[j];
    for (int k = 0; k < 128; ++k) {
        float hv = sh[shidx(k, tid)];
        d1 = fmaf(hv, g1r[k], d1);
        d2 = fmaf(hv, g2r[k], d2);
    }
    float sg = __builtin_amdgcn_rcpf(1.0f + __builtin_amdgcn_exp2f(d1 * -1.442695041f));
    float v  = sg * d2 + resid[(size_t)tid * 128 + j];

    float s = v, ss = v * v;
    #pragma unroll
    for (int m = 1; m < 64; m <<= 1) {
        s  += __shfl_xor(s,  m, 64);
        ss += __shfl_xor(ss, m, 64);
    }
    __syncthreads();
    if ((tid & 63) == 0) { sh[(tid >> 6) * 2] = s; sh[(tid >> 6) * 2 + 1] = ss; }
    __syncthreads();
    s  = sh[0] + sh[2];
    ss = sh[1] + sh[3];
    float mean = s * (1.0f / 128.0f);
    float var  = ss * (1.0f / 128.0f) - mean * mean;
    out[(size_t)tid * 128 + j] = (v - mean) * rsqrtf(var + 1e-5f) * bnw[j] + bnb[j];
}

extern "C" void kernel_launch(void* const* d_in, const int* in_sizes, int n_in,
                              void* d_out, int out_size, void* d_ws, size_t ws_size,
                              hipStream_t stream) {
    const float* x      = (const float*)d_in[0];
    const float* fc1_W1 = (const float*)d_in[1];
    const float* fc1_W2 = (const float*)d_in[2];
    const float* fc1_B1 = (const float*)d_in[3];
    const float* fc1_B2 = (const float*)d_in[4];
    const float* fc2_W1 = (const float*)d_in[5];
    const float* fc2_W2 = (const float*)d_in[6];
    const float* fc2_B1 = (const float*)d_in[7];
    const float* fc2_B2 = (const float*)d_in[8];
    const float* sk_W1  = (const float*)d_in[9];
    const float* sk_W2  = (const float*)d_in[10];
    const float* sk_B1  = (const float*)d_in[11];
    const float* sk_B2  = (const float*)d_in[12];
    const float* g1w    = (const float*)d_in[13];
    const float* g1b    = (const float*)d_in[14];
    const float* g2w    = (const float*)d_in[15];
    const float* g2b    = (const float*)d_in[16];
    const float* bnw    = (const float*)d_in[17];
    const float* bnb    = (const float*)d_in[18];
    float* out = (float*)d_out;

    float* ws    = (float*)d_ws;
    float* h1    = ws;                    // 128*256
    float* h2    = h1 + 128 * 256;        // 128*128
    float* resid = h2 + 128 * 128;        // 128*128
    float* fx    = resid + 128 * 128;     // 128*7*128
    float* fh    = fx + 128 * NF * 128;   // 256*7*128

    hipMemsetAsync(h1, 0, (size_t)(128 * 256 + 2 * 128 * 128) * sizeof(float), stream);

    feats_kernel<<<dim3((128 * BATCH) / 256), 256, 0, stream>>>(x, fx, 128, 0);

    kan_kernel<128, 256, 16><<<dim3(256, 8), 256, 0, stream>>>(
        fx, fc1_W1, fc1_W2, fc1_B1, fc1_B2, h1);
    kan_kernel<128, 128, 8><<<dim3(128, 16), 256, 0, stream>>>(
        fx, sk_W1, sk_W2, sk_B1, sk_B2, resid);

    feats_kernel<<<dim3((256 * BATCH) / 256), 256, 0, stream>>>(h1, fh, 256, 1);

    kan_kernel<256, 128, 16><<<dim3(128, 16), 256, 0, stream>>>(
        fh, fc2_W1, fc2_W2, fc2_B1, fc2_B2, h2);

    glu_bn_kernel<<<dim3(128), 128, 0, stream>>>(
        h2, resid, g1w, g1b, g2w, g2b, bnw, bnb, out);
}

// Round 4
// 153.535 us; speedup vs baseline: 1.0902x; 1.0902x over previous
//
#include <hip/hip_runtime.h>
#include <cstddef>
#include <cstdint>

#define BATCH 128
#define NF 7

typedef float v2f __attribute__((ext_vector_type(2)));

__device__ __forceinline__ v2f silu2(v2f a) {
    v2f t = a * -1.442695041f;
    v2f e;
    e.x = __builtin_amdgcn_exp2f(t.x);
    e.y = __builtin_amdgcn_exp2f(t.y);
    v2f d = e + 1.0f;
    v2f r;
    r.x = __builtin_amdgcn_rcpf(d.x);
    r.y = __builtin_amdgcn_rcpf(d.y);
    return a * r;
}

// feats layout: out[i][f][lane] as float2 {row b, row b+64}
__global__ void feats_kernel(const float* __restrict__ in, float* __restrict__ out,
                             int din, int do_elu) {
    int t = blockIdx.x * blockDim.x + threadIdx.x;
    if (t >= din * BATCH) return;
    int b = t & (BATCH - 1);
    int i = t >> 7;
    float v = in[b * din + i];
    if (do_elu) v = (v > 0.0f) ? v : (__builtin_amdgcn_exp2f(v * 1.442695041f) - 1.0f);
    float s1, c1, s2, c2, s4, c4;
    sincosf(v, &s1, &c1);
    sincosf(2.0f * v, &s2, &c2);
    sincosf(4.0f * v, &s4, &c4);
    float* o = out + (size_t)i * (NF * 128) + (b & 63) * 2 + (b >> 6);
    o[0 * 128] = v;
    o[1 * 128] = s1;
    o[2 * 128] = s2;
    o[3 * 128] = s4;
    o[4 * 128] = c1;
    o[5 * 128] = c2;
    o[6 * 128] = c4;
}

// Weights are wave-uniform per (i,j) task: read them through the SCALAR path
// (s_load -> SGPR) and let v_fma_f32's SGPR-operand broadcast do the fan-out.
// No LDS in the main loop, no barriers until the final reduce.
template <int DIN, int DOUT, int CHUNK>
__global__ __launch_bounds__(256, 8) void kan_kernel(
    const float* __restrict__ fx,   // [DIN][NF][64] of float2 pairs
    const float* __restrict__ W1,   // [DIN][DOUT][32][7]
    const float* __restrict__ W2,   // [DIN][DOUT][32]
    const float* __restrict__ B1,   // [DIN][DOUT][32]
    const float* __restrict__ B2,   // [DIN][DOUT]
    float* __restrict__ out)        // [BATCH][DOUT], pre-zeroed, atomic accum
{
    __shared__ float redbuf[4 * 128];
    const int j    = blockIdx.x;
    const int tid  = threadIdx.x;
    const int w    = tid >> 6;
    const int lane = tid & 63;
    const int i0   = blockIdx.y * CHUNK;

    v2f tot = (v2f)(0.0f);

    for (int t = 0; t < CHUNK / 4; ++t) {
        // force wave-uniform so weight loads become s_load
        const int i = __builtin_amdgcn_readfirstlane(i0 + t * 4 + w);
        const size_t task = (size_t)i * DOUT + j;
        const float* __restrict__ w1p = W1 + task * 224;   // [32][7]
        const float* __restrict__ b1p = B1 + task * 32;
        const float* __restrict__ w2p = W2 + task * 32;

        // ---- per-lane feats: 2 batch rows packed as float2 (VGPR) ----
        const float* fp = fx + (size_t)i * (NF * 128) + lane * 2;
        v2f f[NF];
        #pragma unroll
        for (int ff = 0; ff < NF; ++ff) f[ff] = *(const v2f*)(fp + ff * 128);

        v2f o = (v2f)(0.0f);
        #pragma unroll 1
        for (int hg = 0; hg < 4; ++hg) {          // 4 groups of 8 h: ~72 SGPRs live/group
            #pragma unroll
            for (int hh = 0; hh < 8; ++hh) {
                const int h = hg * 8 + hh;
                const float* wr = w1p + h * 7;
                float b1v = b1p[h];
                float w2v = w2p[h];
                v2f a = {b1v, b1v};
                #pragma unroll
                for (int ff = 0; ff < NF; ++ff) {
                    float wv = wr[ff];             // SGPR operand, free broadcast
                    a.x = fmaf(f[ff].x, wv, a.x);
                    a.y = fmaf(f[ff].y, wv, a.y);
                }
                v2f s = silu2(a);
                o.x = fmaf(s.x, w2v, o.x);
                o.y = fmaf(s.y, w2v, o.y);
            }
        }
        float b2v = B2[task];
        tot += o + b2v;
    }

    // ---- block-level reduce over the 4 waves, then one atomic per (b, j) ----
    redbuf[w * 128 + lane]      = tot.x;
    redbuf[w * 128 + 64 + lane] = tot.y;
    __syncthreads();
    if (tid < 128) {
        float s = redbuf[tid] + redbuf[128 + tid] + redbuf[256 + tid] + redbuf[384 + tid];
        atomicAdd(&out[(size_t)tid * DOUT + j], s);
    }
}

// GLU gate + residual + BatchNorm(batch axis), one block per output column j.
__device__ __forceinline__ int shidx(int k, int b) { return (k << 7) + ((b + k) & 127); }

__global__ __launch_bounds__(128) void glu_bn_kernel(
    const float* __restrict__ h2,     // [BATCH][128]
    const float* __restrict__ resid,  // [BATCH][128]
    const float* __restrict__ g1w, const float* __restrict__ g1b,
    const float* __restrict__ g2w, const float* __restrict__ g2b,
    const float* __restrict__ bnw, const float* __restrict__ bnb,
    float* __restrict__ out)          // [BATCH][128]
{
    __shared__ float sh[128 * 128];
    const int j   = blockIdx.x;
    const int tid = threadIdx.x;

    for (int b2 = 0; b2 < 128; ++b2)
        sh[shidx(tid, b2)] = h2[(size_t)b2 * 128 + tid];
    __syncthreads();

    const float* g1r = g1w + (size_t)j * 128;
    const float* g2r = g2w + (size_t)j * 128;
    float d1 = g1b[j], d2 = g2b[j];
    for (int k = 0; k < 128; ++k) {
        float hv = sh[shidx(k, tid)];
        d1 = fmaf(hv, g1r[k], d1);
        d2 = fmaf(hv, g2r[k], d2);
    }
    float sg = __builtin_amdgcn_rcpf(1.0f + __builtin_amdgcn_exp2f(d1 * -1.442695041f));
    float v  = sg * d2 + resid[(size_t)tid * 128 + j];

    float s = v, ss = v * v;
    #pragma unroll
    for (int m = 1; m < 64; m <<= 1) {
        s  += __shfl_xor(s,  m, 64);
        ss += __shfl_xor(ss, m, 64);
    }
    __syncthreads();
    if ((tid & 63) == 0) { sh[(tid >> 6) * 2] = s; sh[(tid >> 6) * 2 + 1] = ss; }
    __syncthreads();
    s  = sh[0] + sh[2];
    ss = sh[1] + sh[3];
    float mean = s * (1.0f / 128.0f);
    float var  = ss * (1.0f / 128.0f) - mean * mean;
    out[(size_t)tid * 128 + j] = (v - mean) * rsqrtf(var + 1e-5f) * bnw[j] + bnb[j];
}

extern "C" void kernel_launch(void* const* d_in, const int* in_sizes, int n_in,
                              void* d_out, int out_size, void* d_ws, size_t ws_size,
                              hipStream_t stream) {
    const float* x      = (const float*)d_in[0];
    const float* fc1_W1 = (const float*)d_in[1];
    const float* fc1_W2 = (const float*)d_in[2];
    const float* fc1_B1 = (const float*)d_in[3];
    const float* fc1_B2 = (const float*)d_in[4];
    const float* fc2_W1 = (const float*)d_in[5];
    const float* fc2_W2 = (const float*)d_in[6];
    const float* fc2_B1 = (const float*)d_in[7];
    const float* fc2_B2 = (const float*)d_in[8];
    const float* sk_W1  = (const float*)d_in[9];
    const float* sk_W2  = (const float*)d_in[10];
    const float* sk_B1  = (const float*)d_in[11];
    const float* sk_B2  = (const float*)d_in[12];
    const float* g1w    = (const float*)d_in[13];
    const float* g1b    = (const float*)d_in[14];
    const float* g2w    = (const float*)d_in[15];
    const float* g2b    = (const float*)d_in[16];
    const float* bnw    = (const float*)d_in[17];
    const float* bnb    = (const float*)d_in[18];
    float* out = (float*)d_out;

    float* ws    = (float*)d_ws;
    float* h1    = ws;                    // 128*256
    float* h2    = h1 + 128 * 256;        // 128*128
    float* resid = h2 + 128 * 128;        // 128*128
    float* fx    = resid + 128 * 128;     // 128*7*128
    float* fh    = fx + 128 * NF * 128;   // 256*7*128

    hipMemsetAsync(h1, 0, (size_t)(128 * 256 + 2 * 128 * 128) * sizeof(float), stream);

    feats_kernel<<<dim3((128 * BATCH) / 256), 256, 0, stream>>>(x, fx, 128, 0);

    kan_kernel<128, 256, 16><<<dim3(256, 8), 256, 0, stream>>>(
        fx, fc1_W1, fc1_W2, fc1_B1, fc1_B2, h1);
    kan_kernel<128, 128, 8><<<dim3(128, 16), 256, 0, stream>>>(
        fx, sk_W1, sk_W2, sk_B1, sk_B2, resid);

    feats_kernel<<<dim3((256 * BATCH) / 256), 256, 0, stream>>>(h1, fh, 256, 1);

    kan_kernel<256, 128, 16><<<dim3(128, 16), 256, 0, stream>>>(
        fh, fc2_W1, fc2_W2, fc2_B1, fc2_B2, h2);

    glu_bn_kernel<<<dim3(128), 128, 0, stream>>>(
        h2, resid, g1w, g1b, g2w, g2b, bnw, bnb, out);
}